// Round 1
// baseline (2699.762 us; speedup 1.0000x reference)
//
#include <hip/hip_runtime.h>

typedef unsigned short u16;
typedef unsigned int   u32;
typedef __attribute__((ext_vector_type(8))) short bf16x8;
typedef __attribute__((ext_vector_type(4))) float f32x4;

#define GK 768            // K dim of all GEMMs
#define NSTEP 196
#define NBATCH 64
#define NWG 128           // recurrence workgroups
#define CPW 6             // channels per recurrence wg (128*6 = 768)
#define RROWS 18          // 3 gates * CPW

__device__ __forceinline__ u16 f2bf(float f) {
    u32 u = __float_as_uint(f);
    u = (u + 0x7fffu + ((u >> 16) & 1u)) >> 16;
    return (u16)u;
}
__device__ __forceinline__ float bf2f(u16 h) { return __uint_as_float(((u32)h) << 16); }

// ---------------------------------------------------------------------------
// fp32 -> bf16 convert for x, Wx, Wp (Wh converted inside recurrence kernel)
// ---------------------------------------------------------------------------
__global__ __launch_bounds__(256) void cvt_kernel(
    const float4* __restrict__ x, const float4* __restrict__ wx,
    const float4* __restrict__ wp,
    u32* __restrict__ xb, u32* __restrict__ wxb, u32* __restrict__ wpb)
{
    const int N1 = 9633792 / 4, N2 = 1769472 / 4, N3 = 589824 / 4;
    int i = blockIdx.x * 256 + threadIdx.x;
    const float4* src; u32* dst; int off;
    if (i < N1)            { src = x;  dst = xb;  off = i; }
    else if (i < N1 + N2)  { src = wx; dst = wxb; off = i - N1; }
    else                   { src = wp; dst = wpb; off = i - N1 - N2; }
    float4 v = src[off];
    u32 lo = (u32)f2bf(v.x) | ((u32)f2bf(v.y) << 16);
    u32 hi = (u32)f2bf(v.z) | ((u32)f2bf(v.w) << 16);
    dst[(size_t)off * 2]     = lo;
    dst[(size_t)off * 2 + 1] = hi;
}

// ---------------------------------------------------------------------------
// GEMM: out[M][N] = A[M][K] @ B[N][K]^T   (A,B bf16 row-major K-contiguous)
// MODE 1: += bias[col], bf16 out remapped to [n][b][col] with m = b*196+n
// MODE 0: fp32 out at [m][col], no bias
// 128x128 tile, BK=32, 4 waves, 16x16x32 MFMA, padded-LDS reg staging.
// ---------------------------------------------------------------------------
template<int MODE>
__global__ __launch_bounds__(256) void gemm_bt(
    const u16* __restrict__ A, const u16* __restrict__ B,
    const float* __restrict__ bias, void* __restrict__ outv)
{
    __shared__ u16 As[128 * 40];
    __shared__ u16 Bs[128 * 40];
    const int tid  = threadIdx.x;
    const int lane = tid & 63;
    const int wv   = tid >> 6;
    const int m0 = blockIdx.y * 128;
    const int n0 = blockIdx.x * 128;
    const int wm = (wv & 1) * 64;
    const int wn = (wv >> 1) * 64;

    f32x4 acc[4][4];
#pragma unroll
    for (int i = 0; i < 4; ++i)
#pragma unroll
        for (int j = 0; j < 4; ++j) acc[i][j] = (f32x4){0.f, 0.f, 0.f, 0.f};

    // staging: 512 16B-chunks per tile (128 rows x 4), threads take c=tid, tid+256
    const int r0 = tid >> 2, q0 = tid & 3;
    const u16* gA0 = A + (size_t)(m0 + r0)      * GK + q0 * 8;
    const u16* gA1 = A + (size_t)(m0 + r0 + 64) * GK + q0 * 8;
    const u16* gB0 = B + (size_t)(n0 + r0)      * GK + q0 * 8;
    const u16* gB1 = B + (size_t)(n0 + r0 + 64) * GK + q0 * 8;
    u16* sA0 = As + r0 * 40 + q0 * 8;
    u16* sA1 = As + (r0 + 64) * 40 + q0 * 8;
    u16* sB0 = Bs + r0 * 40 + q0 * 8;
    u16* sB1 = Bs + (r0 + 64) * 40 + q0 * 8;

    const int fr = lane & 15, fq = lane >> 4;
    const u16* fA = As + (wm + fr) * 40 + fq * 8;
    const u16* fB = Bs + (wn + fr) * 40 + fq * 8;

    for (int kt = 0; kt < GK / 32; ++kt) {
        uint4 a0 = *(const uint4*)(gA0 + kt * 32);
        uint4 a1 = *(const uint4*)(gA1 + kt * 32);
        uint4 b0 = *(const uint4*)(gB0 + kt * 32);
        uint4 b1 = *(const uint4*)(gB1 + kt * 32);
        __syncthreads();
        *(uint4*)sA0 = a0; *(uint4*)sA1 = a1;
        *(uint4*)sB0 = b0; *(uint4*)sB1 = b1;
        __syncthreads();
        bf16x8 af[4], bfr[4];
#pragma unroll
        for (int mi = 0; mi < 4; ++mi) af[mi]  = *(const bf16x8*)(fA + mi * 16 * 40);
#pragma unroll
        for (int ni = 0; ni < 4; ++ni) bfr[ni] = *(const bf16x8*)(fB + ni * 16 * 40);
#pragma unroll
        for (int mi = 0; mi < 4; ++mi)
#pragma unroll
            for (int ni = 0; ni < 4; ++ni)
                acc[mi][ni] = __builtin_amdgcn_mfma_f32_16x16x32_bf16(
                    af[mi], bfr[ni], acc[mi][ni], 0, 0, 0);
    }

    if (MODE == 1) {
        u16* out = (u16*)outv;
#pragma unroll
        for (int mi = 0; mi < 4; ++mi) {
#pragma unroll
            for (int ni = 0; ni < 4; ++ni) {
                int col = n0 + wn + ni * 16 + fr;
                float bv = bias[col];
#pragma unroll
                for (int r = 0; r < 4; ++r) {
                    int m = m0 + wm + mi * 16 + fq * 4 + r;
                    int b = m / 196;
                    int nn = m - b * 196;
                    u16 hv = f2bf(acc[mi][ni][r] + bv);
                    int other = __shfl_xor((int)hv, 1, 64);
                    if (!(lane & 1)) {
                        u32 packed = (u32)hv | (((u32)(u16)other) << 16);
                        size_t eidx = ((size_t)nn * 64 + (size_t)b) * 2304 + (size_t)col;
                        *((u32*)out + (eidx >> 1)) = packed;
                    }
                }
            }
        }
    } else {
        float* out = (float*)outv;
#pragma unroll
        for (int mi = 0; mi < 4; ++mi) {
#pragma unroll
            for (int ni = 0; ni < 4; ++ni) {
                int col = n0 + wn + ni * 16 + fr;
#pragma unroll
                for (int r = 0; r < 4; ++r) {
                    int m = m0 + wm + mi * 16 + fq * 4 + r;
                    out[(size_t)m * 768 + col] = acc[mi][ni][r];
                }
            }
        }
    }
}

// ---------------------------------------------------------------------------
// Persistent cooperative GRU recurrence.
// 128 wgs x 512 threads. wg owns 6 channels (18 Wh rows, LDS-resident).
// h double-buffered in global (bf16), exchanged via agent-scope atomics +
// monotonic flag barrier. 196 steps, one barrier wait per step.
// ---------------------------------------------------------------------------
__global__ __launch_bounds__(512) void recur_kernel(
    const u16* __restrict__ xz,   // [196][64][2304] bf16 (x proj + bx)
    const float* __restrict__ Wh, // [2304][768] f32
    const float* __restrict__ bh, // [2304] f32
    u16* __restrict__ hs,         // [64][196][768] bf16 out
    u16* hb,                      // 2 x [64][768] bf16 ping-pong
    int* flags)                   // [NWG]
{
    __shared__ u16  Wh_s[32 * 776];   // 18 valid rows padded to 32, +8 col pad
    __shared__ float hz_s[64 * 20];   // h_zrn tile [batch][18 rows padded 20]

    const int tid  = threadIdx.x;
    const int wg   = blockIdx.x;
    const int c0   = wg * CPW;
    const int lane = tid & 63;
    const int wv   = tid >> 6;
    u32* hbu = (u32*)hb;

    // one-time: Wh slice -> LDS (bf16), zero-pad rows 18..31
    for (int idx = tid; idx < 32 * 768; idx += 512) {
        int j = idx / 768, k = idx - j * 768;
        u16 v = 0;
        if (j < RROWS) {
            int gate = j / CPW, i = j - gate * CPW;
            v = f2bf(Wh[(size_t)(gate * 768 + c0 + i) * 768 + k]);
        }
        Wh_s[j * 776 + k] = v;
    }
    // one-time: zero this wg's slice of read-buffer 1 (h_{-1} = 0)
    if (tid < 192) {
        int b = tid / 3, j = tid - b * 3;
        __hip_atomic_store(hbu + ((49152 + b * 768 + c0 + 2 * j) >> 1), 0u,
                           __ATOMIC_RELAXED, __HIP_MEMORY_SCOPE_AGENT);
    }
    __syncthreads();
    if (tid == 0)
        __hip_atomic_store(&flags[wg], 1, __ATOMIC_RELEASE, __HIP_MEMORY_SCOPE_AGENT);

    const int fr = lane & 15, fq = lane >> 4;
    const int mi = wv & 3, ni = wv >> 2;  // 8 waves: 4 m-tiles x 2 n-tiles

    for (int n = 0; n < NSTEP; ++n) {
        // wait: all wgs finished step n-1 (flags >= n+1)
        if (tid < 64) {
            const int target = n + 1;
            for (;;) {
                int v0 = __hip_atomic_load(&flags[lane], __ATOMIC_RELAXED, __HIP_MEMORY_SCOPE_AGENT);
                int v1 = __hip_atomic_load(&flags[lane + 64], __ATOMIC_RELAXED, __HIP_MEMORY_SCOPE_AGENT);
                int v = v0 < v1 ? v0 : v1;
                if (__all(v >= target)) break;
                __builtin_amdgcn_s_sleep(2);
            }
            __builtin_amdgcn_fence(__ATOMIC_ACQUIRE, "agent"); // inv stale L1/L2
        }
        __syncthreads();

        const u16* hrd = hb + ((n + 1) & 1) * 49152;  // read buffer

        // h_zrn tile: wave computes 16 batches x 16 rows, K=768
        {
            f32x4 acc = (f32x4){0.f, 0.f, 0.f, 0.f};
            const u16* ap = hrd + (size_t)(mi * 16 + fr) * 768 + fq * 8;
            const u16* bp = Wh_s + (ni * 16 + fr) * 776 + fq * 8;
#pragma unroll 4
            for (int kk = 0; kk < 24; ++kk) {
                bf16x8 a = *(const bf16x8*)(ap + kk * 32);
                bf16x8 b = *(const bf16x8*)(bp + kk * 32);
                acc = __builtin_amdgcn_mfma_f32_16x16x32_bf16(a, b, acc, 0, 0, 0);
            }
            int col = ni * 16 + fr;
            if (col < RROWS) {
#pragma unroll
                for (int r = 0; r < 4; ++r)
                    hz_s[(mi * 16 + fq * 4 + r) * 20 + col] = acc[r];
            }
        }
        __syncthreads();

        // gates: 64 batches x 6 channels = 384 threads
        if (tid < 384) {
            int b = tid / CPW, i = tid - b * CPW;
            int c = c0 + i;
            size_t xoff = (size_t)n * 147456 + (size_t)b * 2304;
            float xg0 = bf2f(xz[xoff + c]);
            float xg1 = bf2f(xz[xoff + 768 + c]);
            float xg2 = bf2f(xz[xoff + 1536 + c]);
            float hg0 = hz_s[b * 20 + i]           + bh[c];
            float hg1 = hz_s[b * 20 + CPW + i]     + bh[768 + c];
            float hg2 = hz_s[b * 20 + 2 * CPW + i] + bh[1536 + c];
            float z  = 1.f / (1.f + __expf(-(xg0 + hg0)));
            float rr = 1.f / (1.f + __expf(-(xg1 + hg1)));
            float pre = xg2 + rr * hg2;
            float e2 = __expf(-2.f * pre);
            float nc = (1.f - e2) / (1.f + e2);
            float hold = bf2f(hrd[(size_t)b * 768 + c]);
            float hnew = (1.f - z) * nc + z * hold;
            u16 hv = f2bf(hnew);
            int other = __shfl_xor((int)hv, 1, 64);
            if (!(tid & 1)) {
                u32 packed = (u32)hv | (((u32)(u16)other) << 16);
                __hip_atomic_store(hbu + (((n & 1) * 49152 + b * 768 + c) >> 1), packed,
                                   __ATOMIC_RELAXED, __HIP_MEMORY_SCOPE_AGENT);
                __hip_atomic_store((u32*)hs + (((size_t)(b * 196 + n) * 768 + c) >> 1), packed,
                                   __ATOMIC_RELAXED, __HIP_MEMORY_SCOPE_AGENT);
            }
        }
        __syncthreads();  // drains all waves' atomic stores (vmcnt) before flag
        if (tid == 0)
            __hip_atomic_store(&flags[wg], n + 2, __ATOMIC_RELEASE, __HIP_MEMORY_SCOPE_AGENT);
    }
}

// ---------------------------------------------------------------------------
extern "C" void kernel_launch(void* const* d_in, const int* in_sizes, int n_in,
                              void* d_out, int out_size, void* d_ws, size_t ws_size,
                              hipStream_t stream)
{
    const float* x  = (const float*)d_in[0];
    const float* Wx = (const float*)d_in[1];
    const float* bx = (const float*)d_in[2];
    const float* Wh = (const float*)d_in[3];
    const float* bh = (const float*)d_in[4];
    const float* Wp = (const float*)d_in[5];
    float* out = (float*)d_out;

    char* ws = (char*)d_ws;
    size_t off = 0;
    auto wsalloc = [&](size_t bytes) -> void* {
        void* p = ws + off;
        off += (bytes + 255) & ~(size_t)255;
        return p;
    };
    u16* xb   = (u16*)wsalloc(9633792ull * 2);            // x bf16 [12544][768]
    u16* wxb  = (u16*)wsalloc(1769472ull * 2);            // Wx bf16 [2304][768]
    u16* wpb  = (u16*)wsalloc(589824ull * 2);             // Wp bf16 [768][768]
    u16* xzrn = (u16*)wsalloc(196ull * 64 * 2304 * 2);    // [n][b][3C] bf16
    u16* hs   = (u16*)wsalloc(12544ull * 768 * 2);        // [b][n][C] bf16
    u16* hb   = (u16*)wsalloc(2ull * 64 * 768 * 2);       // h ping-pong
    int* flags = (int*)wsalloc(1024);

    // 1) converts
    cvt_kernel<<<11712, 256, 0, stream>>>(
        (const float4*)x, (const float4*)Wx, (const float4*)Wp,
        (u32*)xb, (u32*)wxb, (u32*)wpb);

    // 2) x_zrn = seq @ Wx^T + bx  ->  [n][b][3C] bf16
    gemm_bt<1><<<dim3(18, 98), 256, 0, stream>>>(xb, wxb, bx, (void*)xzrn);

    // 3) cooperative recurrence
    {
        const u16* a0 = xzrn; const float* a1 = Wh; const float* a2 = bh;
        u16* a3 = hs; u16* a4 = hb; int* a5 = flags;
        void* args[6] = { &a0, &a1, &a2, &a3, &a4, &a5 };
        hipLaunchCooperativeKernel((void*)recur_kernel, dim3(NWG), dim3(512),
                                   args, 0, stream);
    }

    // 4) y = hs @ Wp^T -> d_out fp32
    gemm_bt<0><<<dim3(6, 98), 256, 0, stream>>>(hs, wpb, nullptr, (void*)out);
}